// Round 2
// baseline (93745.581 us; speedup 1.0000x reference)
//
#include <hip/hip_runtime.h>
#include <hip/hip_bf16.h>

typedef unsigned int u32;
using bf16_t = __hip_bfloat16;

#define DEVI __device__ __forceinline__

// ---------------- problem constants ----------------
constexpr int T_ = 4096, B_ = 128;
constexpr int CHUNK = 16, NCHUNK = T_ / CHUNK;   // 256 chunks
constexpr int RC = 64, RCH = RC / CHUNK;         // ring slots, ring chunks (4)
constexpr int NBP = 43;                          // ceil(128/3) b-triples
constexpr int NL = 31;                           // total layers

// ---------------- workspace layout (bytes) ----------------
// [0,16K): progress flags u32[33][64] (0,1 = x-proj halves; 2+li = layer li);
//          dtype flag at byte 12288 (probe kernel writes it AFTER the memset)
// xw ring   : RC*B*20 f32
// ring[0..19]  (stack1 outs): RC*B*20 f32 each
// ring[20..29] (stack2 outs): RC*B*12 f32 each (stride 12 keeps rows 16B aligned)
constexpr size_t FLAGS_BYTES = 16384;
constexpr size_t DTYPE_OFF = 12288;
constexpr size_t XW_OFF = FLAGS_BYTES;
constexpr size_t XW_SZ  = (size_t)RC * B_ * 20 * 4;
constexpr size_t R1_OFF = XW_OFF + XW_SZ;
constexpr size_t R1_SZ  = (size_t)RC * B_ * 20 * 4;
constexpr size_t R2_OFF = R1_OFF + 20 * R1_SZ;
constexpr size_t R2_SZ  = (size_t)RC * B_ * 12 * 4;

struct Params {
  const void* x;
  const void* wih0; const void* bih0;   // x-projection weights (20x64), bias
  const void* wih[NL]; const void* whh[NL];
  const void* bih[NL]; const void* bhh[NL];
  char* ws;
  void* out;
};

DEVI float bflo(u32 u) { return __uint_as_float(u << 16); }
DEVI float bfhi(u32 u) { return __uint_as_float(u & 0xffff0000u); }

template <bool F32>
DEVI float ldw(const void* p, int i) {
  if constexpr (F32) return ((const float*)p)[i];
  else return __bfloat162float(((const bf16_t*)p)[i]);
}

DEVI float fast_tanh(float x) {
  // tanh(x) = 1 - 2/(exp2(2*log2e*x)+1); v_exp/v_rcp ~1ulp; maps +-Inf -> +-1
  float e = __builtin_amdgcn_exp2f(x * 2.8853900817779268f);
  return 1.0f - 2.0f * __builtin_amdgcn_rcpf(e + 1.0f);
}

DEVI void wait_ge(u32* f, u32 v) {
  while (__hip_atomic_load(f, __ATOMIC_ACQUIRE, __HIP_MEMORY_SCOPE_AGENT) < v)
    __builtin_amdgcn_s_sleep(1);
}

DEVI void publish(u32* f, u32 v, int lane) {
  __threadfence();  // agent-scope release of ring data before flag
  if (lane == 0)
    __hip_atomic_store(f, v, __ATOMIC_RELEASE, __HIP_MEMORY_SCOPE_AGENT);
}

DEVI float* ring_ptr(char* ws, int li) {
  return (li < 20) ? (float*)(ws + R1_OFF + (size_t)li * R1_SZ)
                   : (float*)(ws + R2_OFF + (size_t)(li - 20) * R2_SZ);
}

// -------- stage P: xw0[t][b][j] = sum_i x[t,b,i]*wih0[j,i] + bih0[j] --------
// two waves per b-triple (thalf = even/odd 8-step halves of each chunk)
template <bool F32>
DEVI void stage_P(const Params& p, u32* prog, int bp3, int thalf, int lane) {
  const int g = lane / 20, j = lane - g * 20;
  const int b = bp3 * 3 + g;
  const bool act = (lane < 60) && (b < B_);
  const int bc = (b < B_) ? b : (B_ - 1);

  float w[64];
#pragma unroll
  for (int i = 0; i < 64; i++) w[i] = ldw<F32>(p.wih0, j * 64 + i);
  const float bi = ldw<F32>(p.bih0, j);

  float* xw = (float*)(p.ws + XW_OFF);
  u32* my  = prog + thalf * 64 + bp3;
  u32* nxt = prog + 2 * 64 + bp3;  // consumer = layer 0

  for (int c = 0; c < NCHUNK; c++) {
    if (c >= RCH) wait_ge(nxt, (u32)(c - RCH + 1));  // ring backpressure
    for (int tt = 0; tt < 8; tt++) {
      const int t = c * CHUNK + thalf * 8 + tt;
      const int slot = t & (RC - 1);
      float acc = bi;
      if constexpr (F32) {
        const float4* xr = (const float4*)p.x + (size_t)(t * B_ + bc) * 16;
#pragma unroll
        for (int q = 0; q < 16; q++) {
          float4 u = xr[q];
          acc = fmaf(u.x, w[4 * q + 0], acc); acc = fmaf(u.y, w[4 * q + 1], acc);
          acc = fmaf(u.z, w[4 * q + 2], acc); acc = fmaf(u.w, w[4 * q + 3], acc);
        }
      } else {
        const uint4* xr = (const uint4*)p.x + (size_t)(t * B_ + bc) * 8;
#pragma unroll
        for (int q = 0; q < 8; q++) {
          uint4 u = xr[q];
          acc = fmaf(bflo(u.x), w[8 * q + 0], acc); acc = fmaf(bfhi(u.x), w[8 * q + 1], acc);
          acc = fmaf(bflo(u.y), w[8 * q + 2], acc); acc = fmaf(bfhi(u.y), w[8 * q + 3], acc);
          acc = fmaf(bflo(u.z), w[8 * q + 4], acc); acc = fmaf(bfhi(u.z), w[8 * q + 5], acc);
          acc = fmaf(bflo(u.w), w[8 * q + 6], acc); acc = fmaf(bfhi(u.w), w[8 * q + 7], acc);
        }
      }
      if (act) xw[(slot * B_ + bc) * 20 + j] = acc;
    }
    publish(my, (u32)(c + 1), lane);
  }
}

// -------- recurrent stage: h_t = tanh(in_t + h_{t-1}@Whh^T + biases) --------
template <int HOUT, int HIN, int SIN, int SOUT, bool PREPROJ, bool LAST, bool F32>
DEVI void stage_R(const float* __restrict__ rin, float* __restrict__ rout,
                  void* __restrict__ dout,
                  const void* wih, const void* whh,
                  const void* bih, const void* bhh,
                  u32* prog, int li, int bp3, int lane) {
  const int g = lane / 20, j = lane - g * 20;  // 20-lane groups, 3 b's per wave
  const int b = bp3 * 3 + g;
  const bool act = (lane < 60) && (b < B_);
  const int bc = (b < B_) ? b : (B_ - 1);
  const int jc = (j < HOUT) ? j : (HOUT - 1);  // clamp weight-row loads
  const int gbase = g * 80;                    // bpermute byte base of my group

  float wh[HOUT];
#pragma unroll
  for (int k = 0; k < HOUT; k++) wh[k] = ldw<F32>(whh, jc * HOUT + k);
  float wi[PREPROJ ? 1 : HIN];
  if constexpr (!PREPROJ) {
#pragma unroll
    for (int i = 0; i < HIN; i++) wi[i] = ldw<F32>(wih, jc * HIN + i);
  }
  float bsum = ldw<F32>(bhh, jc);
  if constexpr (!PREPROJ) bsum += ldw<F32>(bih, jc);

  u32* my  = prog + (2 + li) * 64 + bp3;
  u32* inA = prog + (PREPROJ ? 0 : (1 + li)) * 64 + bp3;
  u32* inB = prog + 1 * 64 + bp3;                       // PREPROJ only
  u32* nxt = prog + (LAST ? 0 : (3 + li)) * 64 + bp3;   // unused if LAST

  float h = 0.0f;  // h0 = 0
  for (int c = 0; c < NCHUNK; c++) {
    wait_ge(inA, (u32)(c + 1));                         // input chunk ready
    if constexpr (PREPROJ) wait_ge(inB, (u32)(c + 1));
    if constexpr (!LAST) {
      if (c >= RCH) wait_ge(nxt, (u32)(c - RCH + 1));   // output ring free
    }
    for (int tt = 0; tt < CHUNK; tt++) {
      const int t = c * CHUNK + tt;
      const int slot = t & (RC - 1);
      float acc = bsum;
      if constexpr (PREPROJ) {
        acc += rin[(slot * B_ + bc) * SIN + j];          // projected input, own j
      } else {
        const float* row = rin + (size_t)(slot * B_ + bc) * SIN;
        float v[HIN];
#pragma unroll
        for (int q = 0; q < HIN / 4; q++) {
          float4 t4 = ((const float4*)row)[q];
          v[4 * q + 0] = t4.x; v[4 * q + 1] = t4.y;
          v[4 * q + 2] = t4.z; v[4 * q + 3] = t4.w;
        }
        if constexpr (HIN % 4 != 0) {  // HIN==10 tail
          float2 t2 = ((const float2*)row)[HIN / 2 - 1];
          v[HIN - 2] = t2.x; v[HIN - 1] = t2.y;
        }
#pragma unroll
        for (int i = 0; i < HIN; i++) acc = fmaf(v[i], wi[i], acc);
      }
      if constexpr (HOUT > 1) {
#pragma unroll
        for (int k = 0; k < HOUT; k++) {
          float hk = __uint_as_float(
              (u32)__builtin_amdgcn_ds_bpermute(gbase + 4 * k, __float_as_int(h)));
          acc = fmaf(hk, wh[k], acc);
        }
      } else {
        acc = fmaf(h, wh[0], acc);  // scalar hidden, no cross-lane needed
      }
      h = fast_tanh(acc);
      if constexpr (LAST) {
        if (act && j == 0) {
          if constexpr (F32) {
            ((float*)dout)[t * B_ + b] = h;
            if (t == T_ - 1) ((float*)dout)[T_ * B_ + b] = h;  // hT
          } else {
            ((bf16_t*)dout)[t * B_ + b] = __float2bfloat16(h);
            if (t == T_ - 1) ((bf16_t*)dout)[T_ * B_ + b] = __float2bfloat16(h);
          }
        }
      } else {
        if (act && j < HOUT) rout[(slot * B_ + bc) * SOUT + j] = h;
      }
    }
    publish(my, (u32)(c + 1), lane);
  }
}

template <bool F32>
DEVI void pipe_body(const Params& p, int bid, int lane) {
  u32* prog = (u32*)p.ws;
  if (bid < 2 * NBP) {  // x-projection stage
    stage_P<F32>(p, prog, bid >> 1, bid & 1, lane);
    return;
  }
  const int r = bid - 2 * NBP;
  const int li = r / NBP;
  const int bp3 = r - li * NBP;
  float* xw = (float*)(p.ws + XW_OFF);
  if (li == 0) {
    stage_R<20, 20, 20, 20, true, false, F32>(xw, ring_ptr(p.ws, 0), nullptr,
        nullptr, p.whh[0], nullptr, p.bhh[0], prog, 0, bp3, lane);
  } else if (li < 20) {
    stage_R<20, 20, 20, 20, false, false, F32>(ring_ptr(p.ws, li - 1), ring_ptr(p.ws, li),
        nullptr, p.wih[li], p.whh[li], p.bih[li], p.bhh[li], prog, li, bp3, lane);
  } else if (li == 20) {
    stage_R<10, 20, 20, 12, false, false, F32>(ring_ptr(p.ws, 19), ring_ptr(p.ws, 20),
        nullptr, p.wih[20], p.whh[20], p.bih[20], p.bhh[20], prog, 20, bp3, lane);
  } else if (li < 30) {
    stage_R<10, 10, 12, 12, false, false, F32>(ring_ptr(p.ws, li - 1), ring_ptr(p.ws, li),
        nullptr, p.wih[li], p.whh[li], p.bih[li], p.bhh[li], prog, li, bp3, lane);
  } else {
    stage_R<1, 10, 12, 4, false, true, F32>(ring_ptr(p.ws, 29), nullptr, p.out,
        p.wih[30], p.whh[30], p.bih[30], p.bhh[30], prog, 30, bp3, lane);
  }
}

// Classify x's dtype by bit pattern: for bf16 pairs the low u16's exponent
// field sits in [0x70,0x82] (values ~N(0,1)) ~100% of the time; for f32 the
// low 16 bits are mantissa bits -> uniform -> ~7% hit rate. Majority of 256.
__global__ __launch_bounds__(64) void dtype_probe(const u32* x, u32* flag) {
  const int lane = threadIdx.x;
  int cnt = 0;
#pragma unroll
  for (int i = 0; i < 4; i++) {
    u32 w = x[lane * 4 + i];
    u32 e = (w >> 7) & 0xFF;
    cnt += (e >= 0x70 && e <= 0x82) ? 1 : 0;
  }
  for (int o = 32; o > 0; o >>= 1) cnt += __shfl_down(cnt, o);
  if (lane == 0) *flag = (cnt >= 128) ? 1u : 0u;  // 1 = bf16
}

// Gated variants: run only if the probe's verdict matches this dtype.
__global__ __launch_bounds__(64) void rnn_pipe_f32(Params p) {
  if (*(const volatile u32*)(p.ws + DTYPE_OFF) != 0u) return;
  pipe_body<true>(p, blockIdx.x, threadIdx.x);
}
__global__ __launch_bounds__(64) void rnn_pipe_bf16(Params p) {
  if (*(const volatile u32*)(p.ws + DTYPE_OFF) != 1u) return;
  pipe_body<false>(p, blockIdx.x, threadIdx.x);
}

extern "C" void kernel_launch(void* const* d_in, const int* in_sizes, int n_in,
                              void* d_out, int out_size, void* d_ws, size_t ws_size,
                              hipStream_t stream) {
  (void)in_sizes; (void)out_size; (void)ws_size;
  if (n_in < 21) return;

  // Two Params variants: per-layer slice offsets are element counts, so byte
  // offsets differ by dtype -- precompute both, let the gate pick the kernel.
  Params pf{}, pb{};
  pf.x = pb.x = d_in[0];
  pf.wih0 = pb.wih0 = d_in[1];
  pf.bih0 = pb.bih0 = d_in[3];
  pf.wih[0] = pb.wih[0] = nullptr;
  pf.whh[0] = pb.whh[0] = d_in[2];
  pf.bih[0] = pb.bih[0] = nullptr;
  pf.bhh[0] = pb.bhh[0] = d_in[4];
  for (int li = 1; li < 20; li++) {
    pf.wih[li] = (const float*)d_in[5] + (li - 1) * 400;
    pf.whh[li] = (const float*)d_in[6] + (li - 1) * 400;
    pf.bih[li] = (const float*)d_in[7] + (li - 1) * 20;
    pf.bhh[li] = (const float*)d_in[8] + (li - 1) * 20;
    pb.wih[li] = (const bf16_t*)d_in[5] + (li - 1) * 400;
    pb.whh[li] = (const bf16_t*)d_in[6] + (li - 1) * 400;
    pb.bih[li] = (const bf16_t*)d_in[7] + (li - 1) * 20;
    pb.bhh[li] = (const bf16_t*)d_in[8] + (li - 1) * 20;
  }
  pf.wih[20] = pb.wih[20] = d_in[9];
  pf.whh[20] = pb.whh[20] = d_in[10];
  pf.bih[20] = pb.bih[20] = d_in[11];
  pf.bhh[20] = pb.bhh[20] = d_in[12];
  for (int li = 21; li < 30; li++) {
    pf.wih[li] = (const float*)d_in[13] + (li - 21) * 100;
    pf.whh[li] = (const float*)d_in[14] + (li - 21) * 100;
    pf.bih[li] = (const float*)d_in[15] + (li - 21) * 10;
    pf.bhh[li] = (const float*)d_in[16] + (li - 21) * 10;
    pb.wih[li] = (const bf16_t*)d_in[13] + (li - 21) * 100;
    pb.whh[li] = (const bf16_t*)d_in[14] + (li - 21) * 100;
    pb.bih[li] = (const bf16_t*)d_in[15] + (li - 21) * 10;
    pb.bhh[li] = (const bf16_t*)d_in[16] + (li - 21) * 10;
  }
  pf.wih[30] = pb.wih[30] = d_in[17];
  pf.whh[30] = pb.whh[30] = d_in[18];
  pf.bih[30] = pb.bih[30] = d_in[19];
  pf.bhh[30] = pb.bhh[30] = d_in[20];
  pf.ws = pb.ws = (char*)d_ws;
  pf.out = pb.out = d_out;

  // memset flags -> probe writes dtype flag -> both gated pipes (mismatched
  // one exits immediately; ~5us overhead). All on `stream`, graph-capturable.
  hipMemsetAsync(d_ws, 0, FLAGS_BYTES, stream);
  dtype_probe<<<1, 64, 0, stream>>>((const u32*)d_in[0],
                                    (u32*)((char*)d_ws + DTYPE_OFF));
  const int grid = 2 * NBP + NL * NBP;
  rnn_pipe_f32<<<grid, 64, 0, stream>>>(pf);
  rnn_pipe_bf16<<<grid, 64, 0, stream>>>(pb);
}

// Round 3
// 2565.472 us; speedup vs baseline: 36.5413x; 36.5413x over previous
//
#include <hip/hip_runtime.h>

#define DEVI __device__ __forceinline__

// ---------------- problem constants ----------------
constexpr int T_ = 4096, B_ = 128;
constexpr int CH = 4, NCH = T_ / CH;   // 1024 chunks of 4 timesteps
constexpr int NWAVE = 15;              // pipeline stages (waves per block)
constexpr int NSTEP = NCH + NWAVE;     // supersteps incl. fill/drain
constexpr int XROW = 68;               // x row padded 64->68 dwords (bank-dealias)

struct P {
  const float* x;
  const float* w1; const float* b1;    // wih0 (20x64), bih0 (20)
  const float* wih[31]; const float* whh[31];
  const float* bih[31]; const float* bhh[31];
  float* out;
};

using Y1 = float[2][CH][3][20];        // stack1 layer output ring (2 chunk slots)
using Y2 = float[2][CH][3][12];        // stack2 ring, rows padded 10->12 (16B align)
using XWB = float[CH][3][20];
using XB = float[CH * 3 * XROW];

DEVI float ftanh(float x) {
  // tanh(x) = 1 - 2/(exp2(2*log2e*x)+1); ~1ulp, maps +-Inf -> +-1
  float e = __builtin_amdgcn_exp2f(x * 2.8853900817779268f);
  return 1.0f - 2.0f * __builtin_amdgcn_rcpf(e + 1.0f);
}

DEVI float dot20(const float* __restrict__ r, const float* w, float acc) {
#pragma unroll
  for (int q = 0; q < 5; q++) {
    float4 a = ((const float4*)r)[q];
    acc = fmaf(a.x, w[4*q+0], acc); acc = fmaf(a.y, w[4*q+1], acc);
    acc = fmaf(a.z, w[4*q+2], acc); acc = fmaf(a.w, w[4*q+3], acc);
  }
  return acc;
}

DEVI float dot10(const float* __restrict__ r, const float* w, float acc) {
  float4 a0 = ((const float4*)r)[0];
  float4 a1 = ((const float4*)r)[1];
  float2 a2 = *(const float2*)(r + 8);
  acc = fmaf(a0.x, w[0], acc); acc = fmaf(a0.y, w[1], acc);
  acc = fmaf(a0.z, w[2], acc); acc = fmaf(a0.w, w[3], acc);
  acc = fmaf(a1.x, w[4], acc); acc = fmaf(a1.y, w[5], acc);
  acc = fmaf(a1.z, w[6], acc); acc = fmaf(a1.w, w[7], acc);
  acc = fmaf(a2.x, w[8], acc); acc = fmaf(a2.y, w[9], acc);
  return acc;
}

// ---- wave 0: stage x chunk into LDS (prefetch 1 ahead) + input projection ----
DEVI void stage_proj(const P& p, int wg, int lane, XB* xbuf, XWB* xw) {
  const int g = (lane < 60) ? lane / 20 : 2;
  const int j = lane % 20;
  float wp[64];
#pragma unroll
  for (int k = 0; k < 64; k++) wp[k] = p.w1[j * 64 + k];
  const float bp = p.b1[j];

  // 3 float4 per lane per chunk: covers CH*3*64 = 768 floats
  int tq[3], dst[3]; size_t srcoff[3];
#pragma unroll
  for (int r = 0; r < 3; r++) {
    int f = lane + 64 * r;            // 0..191 float4-index within chunk
    tq[r] = f / 48;                   // tt within chunk
    int rem = f % 48, gg = rem / 16, qq = rem % 16;
    int bs = wg * 3 + gg; if (bs > B_ - 1) bs = B_ - 1;  // clamp OOB tail
    srcoff[r] = (size_t)bs * 64 + qq * 4;
    dst[r] = (tq[r] * 3 + gg) * XROW + qq * 4;
  }
  float4 pf[3];
  // preload chunk 0
#pragma unroll
  for (int r = 0; r < 3; r++)
    pf[r] = *(const float4*)(p.x + (size_t)tq[r] * (B_ * 64) + srcoff[r]);
#pragma unroll
  for (int r = 0; r < 3; r++) *(float4*)&xbuf[0][dst[r]] = pf[r];

  for (int s = 0; s < NSTEP; s++) {
    const int c = s;
    if (c < NCH) {
      const int sl = c & 1;
      if (c + 1 < NCH) {              // prefetch next chunk (lands during compute)
#pragma unroll
        for (int r = 0; r < 3; r++)
          pf[r] = *(const float4*)(p.x +
              (size_t)((c + 1) * CH + tq[r]) * (B_ * 64) + srcoff[r]);
      }
      for (int tt = 0; tt < CH; tt++) {
        const float* xr = &xbuf[sl][(tt * 3 + g) * XROW];
        float acc = bp;
#pragma unroll
        for (int q = 0; q < 16; q++) {
          float4 a = ((const float4*)xr)[q];
          acc = fmaf(a.x, wp[4*q+0], acc); acc = fmaf(a.y, wp[4*q+1], acc);
          acc = fmaf(a.z, wp[4*q+2], acc); acc = fmaf(a.w, wp[4*q+3], acc);
        }
        if (lane < 60) xw[sl][tt][g][j] = acc;
      }
      if (c + 1 < NCH) {
        const int nsl = (c + 1) & 1;
#pragma unroll
        for (int r = 0; r < 3; r++) *(float4*)&xbuf[nsl][dst[r]] = pf[r];
      }
    }
    __syncthreads();
  }
}

// ---- stack1 pair wave: layers la, la+1 (H=20). FIRST: la==0 reads xw buf ----
template <bool FIRST>
DEVI void pair_s1(const int la, const P& p, const int w, const int lane,
                  Y1* y1, XWB* xw) {
  const int g = (lane < 60) ? lane / 20 : 2;
  const int j = lane % 20;
  const bool wr = lane < 60;
  const int lb = la + 1;
  float whA[20], whB[20], wiB[20];
  float wiA[FIRST ? 1 : 20];
#pragma unroll
  for (int k = 0; k < 20; k++) whA[k] = p.whh[la][j * 20 + k];
#pragma unroll
  for (int k = 0; k < 20; k++) whB[k] = p.whh[lb][j * 20 + k];
#pragma unroll
  for (int k = 0; k < 20; k++) wiB[k] = p.wih[lb][j * 20 + k];
  if constexpr (!FIRST) {
#pragma unroll
    for (int k = 0; k < 20; k++) wiA[k] = p.wih[la][j * 20 + k];
  }
  float bA = p.bhh[la][j];
  if constexpr (!FIRST) bA += p.bih[la][j];   // L0: bih folded into projection
  const float bB = p.bih[lb][j] + p.bhh[lb][j];

  for (int s = 0; s < NSTEP; s++) {
    const int c = s - w;
    if (c >= 0 && c < NCH) {
      const int sl = c & 1;
      for (int tt = 0; tt < CH; tt++) {
        const int t = c * CH + tt;
        float a = bA;
        if constexpr (FIRST) a += xw[sl][tt][g][j];
        else a = dot20(&y1[la - 1][sl][tt][g][0], wiA, a);
        if (t > 0)
          a = dot20(tt ? &y1[la][sl][tt - 1][g][0] : &y1[la][1 - sl][CH - 1][g][0],
                    whA, a);
        const float hA = ftanh(a);
        if (wr) y1[la][sl][tt][g][j] = hA;
        // layer lb consumes la's row just written (same wave: DS-ordered)
        float ab = dot20(&y1[la][sl][tt][g][0], wiB, bB);
        if (t > 0)
          ab = dot20(tt ? &y1[lb][sl][tt - 1][g][0] : &y1[lb][1 - sl][CH - 1][g][0],
                     whB, ab);
        const float hB = ftanh(ab);
        if (wr) y1[lb][sl][tt][g][j] = hB;
      }
    }
    __syncthreads();
  }
}

// ---- wave 11: L20 (20->10) + L21 + L22 ----
DEVI void tri20(const P& p, const int w, const int lane, Y1* y1, Y2* y2) {
  const int g = (lane < 60) ? lane / 20 : 2;
  const int j = lane % 20;
  const int jc = j < 10 ? j : 9;
  const bool wr = (lane < 60) && (j < 10);
  float wh0[10], wi0[20], wh1[10], wi1[10], wh2[10], wi2[10];
#pragma unroll
  for (int k = 0; k < 10; k++) wh0[k] = p.whh[20][jc * 10 + k];
#pragma unroll
  for (int k = 0; k < 20; k++) wi0[k] = p.wih[20][jc * 20 + k];
#pragma unroll
  for (int k = 0; k < 10; k++) { wh1[k] = p.whh[21][jc * 10 + k]; wi1[k] = p.wih[21][jc * 10 + k]; }
#pragma unroll
  for (int k = 0; k < 10; k++) { wh2[k] = p.whh[22][jc * 10 + k]; wi2[k] = p.wih[22][jc * 10 + k]; }
  const float b0 = p.bih[20][jc] + p.bhh[20][jc];
  const float b1v = p.bih[21][jc] + p.bhh[21][jc];
  const float b2v = p.bih[22][jc] + p.bhh[22][jc];

  for (int s = 0; s < NSTEP; s++) {
    const int c = s - w;
    if (c >= 0 && c < NCH) {
      const int sl = c & 1;
      for (int tt = 0; tt < CH; tt++) {
        const int t = c * CH + tt;
        float a = dot20(&y1[19][sl][tt][g][0], wi0, b0);
        if (t > 0) a = dot10(tt ? &y2[0][sl][tt-1][g][0] : &y2[0][1-sl][CH-1][g][0], wh0, a);
        float h = ftanh(a);
        if (wr) y2[0][sl][tt][g][j] = h;
        a = dot10(&y2[0][sl][tt][g][0], wi1, b1v);
        if (t > 0) a = dot10(tt ? &y2[1][sl][tt-1][g][0] : &y2[1][1-sl][CH-1][g][0], wh1, a);
        h = ftanh(a);
        if (wr) y2[1][sl][tt][g][j] = h;
        a = dot10(&y2[1][sl][tt][g][0], wi2, b2v);
        if (t > 0) a = dot10(tt ? &y2[2][sl][tt-1][g][0] : &y2[2][1-sl][CH-1][g][0], wh2, a);
        h = ftanh(a);
        if (wr) y2[2][sl][tt][g][j] = h;
      }
    }
    __syncthreads();
  }
}

// ---- waves 12/13: three H=10 layers l0..l0+2; ring idx: in=l-21, out=l-20 ----
DEVI void tri_s2(const int l0, const P& p, const int w, const int lane, Y2* y2) {
  const int g = (lane < 60) ? lane / 20 : 2;
  const int j = lane % 20;
  const int jc = j < 10 ? j : 9;
  const bool wr = (lane < 60) && (j < 10);
  float wh[3][10], wi[3][10], bs[3];
#pragma unroll
  for (int m = 0; m < 3; m++) {
    const int l = l0 + m;
#pragma unroll
    for (int k = 0; k < 10; k++) { wh[m][k] = p.whh[l][jc * 10 + k]; wi[m][k] = p.wih[l][jc * 10 + k]; }
    bs[m] = p.bih[l][jc] + p.bhh[l][jc];
  }
  for (int s = 0; s < NSTEP; s++) {
    const int c = s - w;
    if (c >= 0 && c < NCH) {
      const int sl = c & 1;
      for (int tt = 0; tt < CH; tt++) {
        const int t = c * CH + tt;
#pragma unroll
        for (int m = 0; m < 3; m++) {
          const int bi = l0 - 21 + m, bo = bi + 1;
          float a = dot10(&y2[bi][sl][tt][g][0], wi[m], bs[m]);
          if (t > 0) a = dot10(tt ? &y2[bo][sl][tt-1][g][0] : &y2[bo][1-sl][CH-1][g][0], wh[m], a);
          const float h = ftanh(a);
          if (wr) y2[bo][sl][tt][g][j] = h;
        }
      }
    }
    __syncthreads();
  }
}

// ---- wave 14: L29 (H=10) + L30 (H=1) + output stores ----
DEVI void tail29(const P& p, const int w, const int wg, const int lane,
                 Y2* y2, float* out) {
  const int g = (lane < 60) ? lane / 20 : 2;
  const int j = lane % 20;
  const int jc = j < 10 ? j : 9;
  const bool wr = (lane < 60) && (j < 10);
  const int b = wg * 3 + g;
  const bool st = (lane < 60) && (j == 0) && (b < B_);
  float wh29[10], wi29[10], wi30[10];
#pragma unroll
  for (int k = 0; k < 10; k++) {
    wh29[k] = p.whh[29][jc * 10 + k];
    wi29[k] = p.wih[29][jc * 10 + k];
    wi30[k] = p.wih[30][k];
  }
  const float b29 = p.bih[29][jc] + p.bhh[29][jc];
  const float b30 = p.bih[30][0] + p.bhh[30][0];
  const float wh30 = p.whh[30][0];
  float h30 = 0.0f;

  for (int s = 0; s < NSTEP; s++) {
    const int c = s - w;
    if (c >= 0 && c < NCH) {
      const int sl = c & 1;
      for (int tt = 0; tt < CH; tt++) {
        const int t = c * CH + tt;
        float a = dot10(&y2[8][sl][tt][g][0], wi29, b29);
        if (t > 0) a = dot10(tt ? &y2[9][sl][tt-1][g][0] : &y2[9][1-sl][CH-1][g][0], wh29, a);
        const float h = ftanh(a);
        if (wr) y2[9][sl][tt][g][j] = h;
        float a3 = dot10(&y2[9][sl][tt][g][0], wi30, b30);
        a3 = fmaf(h30, wh30, a3);
        h30 = ftanh(a3);
        if (st) {
          out[t * B_ + b] = h30;
          if (t == T_ - 1) out[T_ * B_ + b] = h30;   // hT
        }
      }
    }
    __syncthreads();
  }
}

__global__ __launch_bounds__(960) void rnn_fused(P p) {
  __shared__ float xbuf[2][CH * 3 * XROW];     //  6.5 KB staged x
  __shared__ float xwb[2][CH][3][20];          //  1.9 KB projected input
  __shared__ float y1[20][2][CH][3][20];       // 38.4 KB stack1 rings
  __shared__ float y2[10][2][CH][3][12];       // 11.5 KB stack2 rings
  const int w = threadIdx.x >> 6, lane = threadIdx.x & 63, wg = blockIdx.x;
  if (w == 0)       stage_proj(p, wg, lane, xbuf, xwb);
  else if (w == 1)  pair_s1<true>(0, p, 1, lane, y1, xwb);
  else if (w <= 10) pair_s1<false>(2 * (w - 1), p, w, lane, y1, xwb);
  else if (w == 11) tri20(p, 11, lane, y1, y2);
  else if (w == 12) tri_s2(23, p, 12, lane, y2);
  else if (w == 13) tri_s2(26, p, 13, lane, y2);
  else              tail29(p, 14, wg, lane, y2, p.out);
}

extern "C" void kernel_launch(void* const* d_in, const int* in_sizes, int n_in,
                              void* d_out, int out_size, void* d_ws, size_t ws_size,
                              hipStream_t stream) {
  (void)in_sizes; (void)out_size; (void)d_ws; (void)ws_size;
  if (n_in < 21) return;
  P p{};
  p.x  = (const float*)d_in[0];
  p.w1 = (const float*)d_in[1];    // s1_wih0 (20x64)
  p.b1 = (const float*)d_in[3];    // s1_bih0
  p.wih[0] = nullptr;              p.whh[0] = (const float*)d_in[2];
  p.bih[0] = nullptr;              p.bhh[0] = (const float*)d_in[4];
  for (int l = 1; l < 20; l++) {
    p.wih[l] = (const float*)d_in[5] + (l - 1) * 400;
    p.whh[l] = (const float*)d_in[6] + (l - 1) * 400;
    p.bih[l] = (const float*)d_in[7] + (l - 1) * 20;
    p.bhh[l] = (const float*)d_in[8] + (l - 1) * 20;
  }
  p.wih[20] = (const float*)d_in[9];   p.whh[20] = (const float*)d_in[10];
  p.bih[20] = (const float*)d_in[11];  p.bhh[20] = (const float*)d_in[12];
  for (int l = 21; l < 30; l++) {
    p.wih[l] = (const float*)d_in[13] + (l - 21) * 100;
    p.whh[l] = (const float*)d_in[14] + (l - 21) * 100;
    p.bih[l] = (const float*)d_in[15] + (l - 21) * 10;
    p.bhh[l] = (const float*)d_in[16] + (l - 21) * 10;
  }
  p.wih[30] = (const float*)d_in[17];  p.whh[30] = (const float*)d_in[18];
  p.bih[30] = (const float*)d_in[19];  p.bhh[30] = (const float*)d_in[20];
  p.out = (float*)d_out;

  rnn_fused<<<43, 960, 0, stream>>>(p);
}

// Round 4
// 2540.848 us; speedup vs baseline: 36.8954x; 1.0097x over previous
//
#include <hip/hip_runtime.h>

#define DEVI __device__ __forceinline__
typedef float f2 __attribute__((ext_vector_type(2)));

// ---------------- problem constants ----------------
constexpr int T_ = 4096, B_ = 128;
constexpr int CH = 4, NCH = T_ / CH;   // 1024 chunks of 4 timesteps
constexpr int NSTEP2 = 1040;           // >= NCH + 15 stages, even
constexpr int XROW = 68;               // x row padded 64->68 dwords

// LDS strides in floats.
// y1/xw layer block: [2][CH][3][20]  -> sl*240 + tt*60 + g*20 + j
// y2 layer block:    [2][CH][3][12]  -> sl*144 + tt*36 + g*12 + j
constexpr int Y1L = 480, Y2L = 288;

struct P {
  const float* x;
  const float* w1; const float* b1;    // wih0 (20x64), bih0 (20)
  const float* wih[31]; const float* whh[31];
  const float* bih[31]; const float* bhh[31];
  float* out;
};

DEVI float ftanh(float x) {
  // tanh(x) = 1 - 2/(exp2(2*log2e*x)+1); ~1ulp, maps +-Inf -> +-1
  float e = __builtin_amdgcn_exp2f(x * 2.8853900817779268f);
  return 1.0f - 2.0f * __builtin_amdgcn_rcpf(e + 1.0f);
}

DEVI f2 pfma(f2 a, f2 b, f2 c) { return __builtin_elementwise_fma(a, b, c); }

// dot over 20 floats, packed: 5 ds_read_b128 + 10 v_pk_fma_f32
DEVI void acc20(f2& a, const float* r, const f2* w) {
#pragma unroll
  for (int q = 0; q < 5; q++) {
    float4 v = ((const float4*)r)[q];
    union { float4 f; f2 h[2]; } u; u.f = v;
    a = pfma(u.h[0], w[2 * q], a);
    a = pfma(u.h[1], w[2 * q + 1], a);
  }
}

// dot over 10 floats: 2 b128 + 1 b64 reads + 5 v_pk_fma_f32
DEVI void acc10(f2& a, const float* r, const f2* w) {
  float4 v0 = ((const float4*)r)[0];
  float4 v1 = ((const float4*)r)[1];
  float2 v2 = *(const float2*)(r + 8);
  union { float4 f; f2 h[2]; } u0, u1; u0.f = v0; u1.f = v1;
  f2 t; t.x = v2.x; t.y = v2.y;
  a = pfma(u0.h[0], w[0], a);
  a = pfma(u0.h[1], w[1], a);
  a = pfma(u1.h[0], w[2], a);
  a = pfma(u1.h[1], w[3], a);
  a = pfma(t, w[4], a);
}

// ================= wave 0: x staging + input projection =================
template <int SL>
DEVI void proj_chunk(const float* xb, float* xww, const f2* wp, float bp,
                     int g, bool wr) {
#pragma unroll
  for (int tt = 0; tt < CH; tt++) {
    const float* xr = xb + SL * (CH * 3 * XROW) + (tt * 3 + g) * XROW;
    f2 a; a.x = bp; a.y = 0.f;
#pragma unroll
    for (int q = 0; q < 16; q++) {
      float4 v = ((const float4*)xr)[q];
      union { float4 f; f2 h[2]; } u; u.f = v;
      a = pfma(u.h[0], wp[2 * q], a);
      a = pfma(u.h[1], wp[2 * q + 1], a);
    }
    if (wr) xww[SL * 240 + tt * 60] = a.x + a.y;
  }
}

DEVI void stage_proj(const P& p, int wg, int lane, float* xb, float* xwf) {
  const int g = (lane < 60) ? lane / 20 : 2;
  const int j = lane % 20;
  const bool wr = lane < 60;
  f2 wp[32];
#pragma unroll
  for (int k = 0; k < 32; k++) {
    wp[k].x = p.w1[j * 64 + 2 * k]; wp[k].y = p.w1[j * 64 + 2 * k + 1];
  }
  const float bp = p.b1[j];
  float* xww = xwf + g * 20 + j;

  // 3 float4 per lane per chunk: covers CH*3*64 = 768 floats
  int dst[3]; const float* src[3];
#pragma unroll
  for (int r = 0; r < 3; r++) {
    int f = lane + 64 * r;
    int tq = f / 48, rem = f % 48, gg = rem / 16, qq = rem % 16;
    int bs = wg * 3 + gg; if (bs > B_ - 1) bs = B_ - 1;
    src[r] = p.x + (size_t)tq * (B_ * 64) + (size_t)bs * 64 + qq * 4;
    dst[r] = (tq * 3 + gg) * XROW + qq * 4;
  }
  float4 pf[3];
#pragma unroll
  for (int r = 0; r < 3; r++) pf[r] = *(const float4*)src[r];
#pragma unroll
  for (int r = 0; r < 3; r++) *(float4*)(xb + dst[r]) = pf[r];
#pragma unroll
  for (int r = 0; r < 3; r++) src[r] += CH * B_ * 64;

  for (int s = 0; s < NSTEP2; s += 2) {
    {  // phase A: c = s, slot 0
      const int c = s;
      if (c < NCH) {
        const bool more = (c + 1 < NCH);
        if (more) {
#pragma unroll
          for (int r = 0; r < 3; r++) pf[r] = *(const float4*)src[r];
#pragma unroll
          for (int r = 0; r < 3; r++) src[r] += CH * B_ * 64;
        }
        proj_chunk<0>(xb, xww, wp, bp, g, wr);
        if (more) {
#pragma unroll
          for (int r = 0; r < 3; r++)
            *(float4*)(xb + CH * 3 * XROW + dst[r]) = pf[r];  // slot 1
        }
      }
      __syncthreads();
    }
    {  // phase B: c = s+1, slot 1
      const int c = s + 1;
      if (c < NCH) {
        const bool more = (c + 1 < NCH);
        if (more) {
#pragma unroll
          for (int r = 0; r < 3; r++) pf[r] = *(const float4*)src[r];
#pragma unroll
          for (int r = 0; r < 3; r++) src[r] += CH * B_ * 64;
        }
        proj_chunk<1>(xb, xww, wp, bp, g, wr);
        if (more) {
#pragma unroll
          for (int r = 0; r < 3; r++) *(float4*)(xb + dst[r]) = pf[r];  // slot 0
        }
      }
      __syncthreads();
    }
  }
}

// ================= stack1 pair wave (2 layers, H=20) =================
template <int SL, bool FIRST>
DEVI void pair_chunk(const float* yin, const float* yAr, float* yAw,
                     const float* yBr, float* yBw,
                     const f2* wiA, const f2* whA, const f2* wiB, const f2* whB,
                     float bA, float bB, bool wr) {
#pragma unroll
  for (int tt = 0; tt < CH; tt++) {
    const int IN = SL * 240 + tt * 60;
    const int PV = tt ? (SL * 240 + (tt - 1) * 60) : ((1 - SL) * 240 + 180);
    f2 a; a.x = bA; a.y = 0.f;
    if constexpr (FIRST) a.x += yin[IN];
    else acc20(a, yin + IN, wiA);
    acc20(a, yAr + PV, whA);
    const float hA = ftanh(a.x + a.y);
    if (wr) yAw[IN] = hA;
    f2 b; b.x = bB; b.y = 0.f;
    acc20(b, yAr + IN, wiB);   // reads row just written (same wave, DS-ordered)
    acc20(b, yBr + PV, whB);
    const float hB = ftanh(b.x + b.y);
    if (wr) yBw[IN] = hB;
  }
}

template <bool PH, bool FIRST>
DEVI void pair_s1(int la, int w, const P& p, int lane, float* y1f, float* xwf) {
  const int g = (lane < 60) ? lane / 20 : 2;
  const int j = lane % 20;
  const bool wr = lane < 60;
  const int lb = la + 1;
  f2 whA[10], whB[10], wiB[10], wiA[FIRST ? 1 : 10];
#pragma unroll
  for (int k = 0; k < 10; k++) {
    whA[k].x = p.whh[la][j * 20 + 2 * k]; whA[k].y = p.whh[la][j * 20 + 2 * k + 1];
    whB[k].x = p.whh[lb][j * 20 + 2 * k]; whB[k].y = p.whh[lb][j * 20 + 2 * k + 1];
    wiB[k].x = p.wih[lb][j * 20 + 2 * k]; wiB[k].y = p.wih[lb][j * 20 + 2 * k + 1];
  }
  if constexpr (!FIRST) {
#pragma unroll
    for (int k = 0; k < 10; k++) {
      wiA[k].x = p.wih[la][j * 20 + 2 * k]; wiA[k].y = p.wih[la][j * 20 + 2 * k + 1];
    }
  }
  float bA = p.bhh[la][j];
  if constexpr (!FIRST) bA += p.bih[la][j];  // L0: bih folded into projection
  const float bB = p.bih[lb][j] + p.bhh[lb][j];

  const float* yin = FIRST ? (xwf + g * 20 + j) : (y1f + (la - 1) * Y1L + g * 20);
  const float* yAr = y1f + la * Y1L + g * 20;
  float*       yAw = y1f + la * Y1L + g * 20 + j;
  const float* yBr = y1f + lb * Y1L + g * 20;
  float*       yBw = y1f + lb * Y1L + g * 20 + j;
  if (wr) { yAw[420] = 0.f; yBw[420] = 0.f; }  // zero slot[1][CH-1] => drop t>0 branch

  for (int s = 0; s < NSTEP2; s += 2) {
    if ((unsigned)(s - w) < (unsigned)NCH)
      pair_chunk<PH ? 1 : 0, FIRST>(yin, yAr, yAw, yBr, yBw, wiA, whA, wiB, whB, bA, bB, wr);
    __syncthreads();
    if ((unsigned)(s + 1 - w) < (unsigned)NCH)
      pair_chunk<PH ? 0 : 1, FIRST>(yin, yAr, yAw, yBr, yBw, wiA, whA, wiB, whB, bA, bB, wr);
    __syncthreads();
  }
}

// ================= wave 11: L20 (20->10) + L21 + L22 =================
template <int SL>
DEVI void tri20_chunk(const float* y19, const float* y0r, float* y0w,
                      const float* y1r, float* y1w, const float* y2r, float* y2w,
                      const f2* wi0, const f2* wh0, const f2* wi1, const f2* wh1,
                      const f2* wi2, const f2* wh2,
                      float b0, float b1, float b2, bool wr) {
#pragma unroll
  for (int tt = 0; tt < CH; tt++) {
    const int IN1 = SL * 240 + tt * 60;
    const int IN2 = SL * 144 + tt * 36;
    const int PV2 = tt ? (SL * 144 + (tt - 1) * 36) : ((1 - SL) * 144 + 108);
    f2 a; a.x = b0; a.y = 0.f;
    acc20(a, y19 + IN1, wi0);
    acc10(a, y0r + PV2, wh0);
    float h = ftanh(a.x + a.y);
    if (wr) y0w[IN2] = h;
    a.x = b1; a.y = 0.f;
    acc10(a, y0r + IN2, wi1);
    acc10(a, y1r + PV2, wh1);
    h = ftanh(a.x + a.y);
    if (wr) y1w[IN2] = h;
    a.x = b2; a.y = 0.f;
    acc10(a, y1r + IN2, wi2);
    acc10(a, y2r + PV2, wh2);
    h = ftanh(a.x + a.y);
    if (wr) y2w[IN2] = h;
  }
}

template <bool PH>
DEVI void tri20(const P& p, int w, int lane, float* y1f, float* y2f) {
  const int g = (lane < 60) ? lane / 20 : 2;
  const int j = lane % 20;
  const int jc = j < 10 ? j : 9;
  const bool wr = (lane < 60) && (j < 10);
  f2 wi0[10], wh0[5], wi1[5], wh1[5], wi2[5], wh2[5];
#pragma unroll
  for (int k = 0; k < 10; k++) {
    wi0[k].x = p.wih[20][jc * 20 + 2 * k]; wi0[k].y = p.wih[20][jc * 20 + 2 * k + 1];
  }
#pragma unroll
  for (int k = 0; k < 5; k++) {
    wh0[k].x = p.whh[20][jc * 10 + 2 * k]; wh0[k].y = p.whh[20][jc * 10 + 2 * k + 1];
    wi1[k].x = p.wih[21][jc * 10 + 2 * k]; wi1[k].y = p.wih[21][jc * 10 + 2 * k + 1];
    wh1[k].x = p.whh[21][jc * 10 + 2 * k]; wh1[k].y = p.whh[21][jc * 10 + 2 * k + 1];
    wi2[k].x = p.wih[22][jc * 10 + 2 * k]; wi2[k].y = p.wih[22][jc * 10 + 2 * k + 1];
    wh2[k].x = p.whh[22][jc * 10 + 2 * k]; wh2[k].y = p.whh[22][jc * 10 + 2 * k + 1];
  }
  const float b0 = p.bih[20][jc] + p.bhh[20][jc];
  const float b1 = p.bih[21][jc] + p.bhh[21][jc];
  const float b2 = p.bih[22][jc] + p.bhh[22][jc];

  const float* y19 = y1f + 19 * Y1L + g * 20;
  const float* y0r = y2f + 0 * Y2L + g * 12;  float* y0w = y2f + 0 * Y2L + g * 12 + j;
  const float* y1r = y2f + 1 * Y2L + g * 12;  float* y1w = y2f + 1 * Y2L + g * 12 + j;
  const float* y2r = y2f + 2 * Y2L + g * 12;  float* y2w = y2f + 2 * Y2L + g * 12 + j;
  if (wr) { y0w[252] = 0.f; y1w[252] = 0.f; y2w[252] = 0.f; }  // slot[1][CH-1]

  for (int s = 0; s < NSTEP2; s += 2) {
    if ((unsigned)(s - w) < (unsigned)NCH)
      tri20_chunk<PH ? 1 : 0>(y19, y0r, y0w, y1r, y1w, y2r, y2w,
                              wi0, wh0, wi1, wh1, wi2, wh2, b0, b1, b2, wr);
    __syncthreads();
    if ((unsigned)(s + 1 - w) < (unsigned)NCH)
      tri20_chunk<PH ? 0 : 1>(y19, y0r, y0w, y1r, y1w, y2r, y2w,
                              wi0, wh0, wi1, wh1, wi2, wh2, b0, b1, b2, wr);
    __syncthreads();
  }
}

// ================= waves 12/13: three H=10 layers =================
template <int SL>
DEVI void tri_chunk(const float* yi0, const float* r0, float* w0,
                    const float* r1, float* w1, const float* r2, float* w2,
                    const f2 wi[3][5], const f2 wh[3][5], const float* bs, bool wr) {
#pragma unroll
  for (int tt = 0; tt < CH; tt++) {
    const int IN2 = SL * 144 + tt * 36;
    const int PV2 = tt ? (SL * 144 + (tt - 1) * 36) : ((1 - SL) * 144 + 108);
    f2 a; a.x = bs[0]; a.y = 0.f;
    acc10(a, yi0 + IN2, wi[0]);
    acc10(a, r0 + PV2, wh[0]);
    float h = ftanh(a.x + a.y);
    if (wr) w0[IN2] = h;
    a.x = bs[1]; a.y = 0.f;
    acc10(a, r0 + IN2, wi[1]);
    acc10(a, r1 + PV2, wh[1]);
    h = ftanh(a.x + a.y);
    if (wr) w1[IN2] = h;
    a.x = bs[2]; a.y = 0.f;
    acc10(a, r1 + IN2, wi[2]);
    acc10(a, r2 + PV2, wh[2]);
    h = ftanh(a.x + a.y);
    if (wr) w2[IN2] = h;
  }
}

template <bool PH>
DEVI void tri_s2(int l0, int w, const P& p, int lane, float* y2f) {
  const int g = (lane < 60) ? lane / 20 : 2;
  const int j = lane % 20;
  const int jc = j < 10 ? j : 9;
  const bool wr = (lane < 60) && (j < 10);
  f2 wi[3][5], wh[3][5];
  float bs[3];
#pragma unroll
  for (int m = 0; m < 3; m++) {
    const int l = l0 + m;
#pragma unroll
    for (int k = 0; k < 5; k++) {
      wi[m][k].x = p.wih[l][jc * 10 + 2 * k]; wi[m][k].y = p.wih[l][jc * 10 + 2 * k + 1];
      wh[m][k].x = p.whh[l][jc * 10 + 2 * k]; wh[m][k].y = p.whh[l][jc * 10 + 2 * k + 1];
    }
    bs[m] = p.bih[l][jc] + p.bhh[l][jc];
  }
  const int bi = l0 - 21;  // input ring index
  const float* yi0 = y2f + bi * Y2L + g * 12;
  const float* r0 = y2f + (bi + 1) * Y2L + g * 12;  float* w0 = y2f + (bi + 1) * Y2L + g * 12 + j;
  const float* r1 = y2f + (bi + 2) * Y2L + g * 12;  float* w1 = y2f + (bi + 2) * Y2L + g * 12 + j;
  const float* r2 = y2f + (bi + 3) * Y2L + g * 12;  float* w2 = y2f + (bi + 3) * Y2L + g * 12 + j;
  if (wr) { w0[252] = 0.f; w1[252] = 0.f; w2[252] = 0.f; }

  for (int s = 0; s < NSTEP2; s += 2) {
    if ((unsigned)(s - w) < (unsigned)NCH)
      tri_chunk<PH ? 1 : 0>(yi0, r0, w0, r1, w1, r2, w2, wi, wh, bs, wr);
    __syncthreads();
    if ((unsigned)(s + 1 - w) < (unsigned)NCH)
      tri_chunk<PH ? 0 : 1>(yi0, r0, w0, r1, w1, r2, w2, wi, wh, bs, wr);
    __syncthreads();
  }
}

// ================= wave 14: L29 (H=10) + L30 (H=1) + stores =================
template <int SL>
DEVI void tail_chunk(const float* y8r, const float* y9r, float* y9w,
                     const f2* wi29, const f2* wh29, const f2* wi30,
                     float b29, float b30, float wh30, float& h30,
                     float*& optr, bool wr, bool st) {
#pragma unroll
  for (int tt = 0; tt < CH; tt++) {
    const int IN2 = SL * 144 + tt * 36;
    const int PV2 = tt ? (SL * 144 + (tt - 1) * 36) : ((1 - SL) * 144 + 108);
    f2 a; a.x = b29; a.y = 0.f;
    acc10(a, y8r + IN2, wi29);
    acc10(a, y9r + PV2, wh29);
    const float h = ftanh(a.x + a.y);
    if (wr) y9w[IN2] = h;
    f2 a3; a3.x = b30; a3.y = 0.f;
    acc10(a3, y9r + IN2, wi30);
    h30 = ftanh(fmaf(h30, wh30, a3.x + a3.y));
    if (st) optr[tt * B_] = h30;
  }
  optr += CH * B_;
}

template <bool PH>
DEVI void tail29(const P& p, int w, int wg, int lane, float* y2f) {
  const int g = (lane < 60) ? lane / 20 : 2;
  const int j = lane % 20;
  const int jc = j < 10 ? j : 9;
  const bool wr = (lane < 60) && (j < 10);
  const int b = wg * 3 + g;
  const bool st = (lane < 60) && (j == 0) && (b < B_);
  f2 wi29[5], wh29[5], wi30[5];
#pragma unroll
  for (int k = 0; k < 5; k++) {
    wi29[k].x = p.wih[29][jc * 10 + 2 * k]; wi29[k].y = p.wih[29][jc * 10 + 2 * k + 1];
    wh29[k].x = p.whh[29][jc * 10 + 2 * k]; wh29[k].y = p.whh[29][jc * 10 + 2 * k + 1];
    wi30[k].x = p.wih[30][2 * k];           wi30[k].y = p.wih[30][2 * k + 1];
  }
  const float b29 = p.bih[29][jc] + p.bhh[29][jc];
  const float b30 = p.bih[30][0] + p.bhh[30][0];
  const float wh30 = p.whh[30][0];
  float h30 = 0.0f;
  const float* y8r = y2f + 8 * Y2L + g * 12;
  const float* y9r = y2f + 9 * Y2L + g * 12;
  float*       y9w = y2f + 9 * Y2L + g * 12 + j;
  if (wr) y9w[252] = 0.f;
  float* optr = p.out + ((b < B_) ? b : (B_ - 1));

  for (int s = 0; s < NSTEP2; s += 2) {
    if ((unsigned)(s - w) < (unsigned)NCH)
      tail_chunk<PH ? 1 : 0>(y8r, y9r, y9w, wi29, wh29, wi30, b29, b30, wh30, h30, optr, wr, st);
    __syncthreads();
    if ((unsigned)(s + 1 - w) < (unsigned)NCH)
      tail_chunk<PH ? 0 : 1>(y8r, y9r, y9w, wi29, wh29, wi30, b29, b30, wh30, h30, optr, wr, st);
    __syncthreads();
  }
  if (st) p.out[T_ * B_ + b] = h30;  // hT
}

// ================= kernel =================
__global__ __launch_bounds__(960, 4) void rnn_fused(P p) {
  __shared__ float xbuf[2 * CH * 3 * XROW];   //  6.5 KB staged x
  __shared__ float xw[2 * CH * 3 * 20];       //  1.9 KB projected input
  __shared__ float y1[20 * Y1L];              // 38.4 KB stack1 rings
  __shared__ float y2[10 * Y2L];              // 11.5 KB stack2 rings
  const int w = threadIdx.x >> 6, lane = threadIdx.x & 63, wg = blockIdx.x;
  if (w == 0)       stage_proj(p, wg, lane, xbuf, xw);
  else if (w == 1)  pair_s1<true, true>(0, 1, p, lane, y1, xw);
  else if (w <= 10) {
    const int la = 2 * (w - 1);
    if (w & 1) pair_s1<true, false>(la, w, p, lane, y1, xw);
    else       pair_s1<false, false>(la, w, p, lane, y1, xw);
  }
  else if (w == 11) tri20<true>(p, 11, lane, y1, y2);
  else if (w == 12) tri_s2<false>(23, 12, p, lane, y2);
  else if (w == 13) tri_s2<true>(26, 13, p, lane, y2);
  else              tail29<false>(p, 14, wg, lane, y2);
}

extern "C" void kernel_launch(void* const* d_in, const int* in_sizes, int n_in,
                              void* d_out, int out_size, void* d_ws, size_t ws_size,
                              hipStream_t stream) {
  (void)in_sizes; (void)out_size; (void)d_ws; (void)ws_size;
  if (n_in < 21) return;
  P p{};
  p.x  = (const float*)d_in[0];
  p.w1 = (const float*)d_in[1];    // s1_wih0 (20x64)
  p.b1 = (const float*)d_in[3];    // s1_bih0
  p.wih[0] = nullptr;              p.whh[0] = (const float*)d_in[2];
  p.bih[0] = nullptr;              p.bhh[0] = (const float*)d_in[4];
  for (int l = 1; l < 20; l++) {
    p.wih[l] = (const float*)d_in[5] + (l - 1) * 400;
    p.whh[l] = (const float*)d_in[6] + (l - 1) * 400;
    p.bih[l] = (const float*)d_in[7] + (l - 1) * 20;
    p.bhh[l] = (const float*)d_in[8] + (l - 1) * 20;
  }
  p.wih[20] = (const float*)d_in[9];   p.whh[20] = (const float*)d_in[10];
  p.bih[20] = (const float*)d_in[11];  p.bhh[20] = (const float*)d_in[12];
  for (int l = 21; l < 30; l++) {
    p.wih[l] = (const float*)d_in[13] + (l - 21) * 100;
    p.whh[l] = (const float*)d_in[14] + (l - 21) * 100;
    p.bih[l] = (const float*)d_in[15] + (l - 21) * 10;
    p.bhh[l] = (const float*)d_in[16] + (l - 21) * 10;
  }
  p.wih[30] = (const float*)d_in[17];  p.whh[30] = (const float*)d_in[18];
  p.bih[30] = (const float*)d_in[19];  p.bhh[30] = (const float*)d_in[20];
  p.out = (float*)d_out;

  rnn_fused<<<43, 960, 0, stream>>>(p);
}